// Round 1
// baseline (335.429 us; speedup 1.0000x reference)
//
#include <hip/hip_runtime.h>

typedef short short8 __attribute__((ext_vector_type(8)));
typedef float float4v __attribute__((ext_vector_type(4)));
typedef unsigned short ushort_t;

#define INV_EXT (1.0f / 0.048f)
#define HN 32
#define KK 15
#define CIN 64
#define COUT 64
#define KC 960   /* 15*64 */
#define PB 16    /* points per block */

__device__ inline ushort_t f32_bf16(float f) {
    unsigned int u = __float_as_uint(f);
    u += 0x7FFFu + ((u >> 16) & 1u);   // round-to-nearest-even
    return (ushort_t)(u >> 16);
}

// ---- swizzled LDS element-index helpers (bf16 elems; granule = 8 elems = 16B) ----
__device__ inline int wtIdx(int p, int kc) {               // wtS[p][kc], swizzle by p
    return p * KC + ((((kc >> 3) ^ (p & 7)) << 3) | (kc & 7));
}
__device__ inline int wIdx(int p, int k, int h) {          // wS[p][k][h], swizzle by k
    return ((p << 4) + k) * 32 + ((((h >> 3) ^ (k & 3)) << 3) | (h & 7));
}
__device__ inline int ftIdx(int c, int h) {                // featT[c][h], swizzle by c
    return (c << 5) + ((((h >> 3) ^ (c & 3)) << 3) | (h & 7));
}

// ================= K1: main KPConv =================
template <bool XB>
__global__ __launch_bounds__(256, 2)
void kpconv_main(const float* __restrict__ q_pts,
                 const float* __restrict__ s_pts,
                 const int*   __restrict__ inds,
                 const float* __restrict__ x,
                 const float* __restrict__ kpts,
                 const ushort_t* __restrict__ WT,   // [64][960] bf16 (W transposed)
                 const ushort_t* __restrict__ xb,   // [N][64] bf16 (if XB)
                 float* __restrict__ out, int N)
{
    __shared__ __align__(16) float nbr[PB * HN * 4];   // 8 KB: dx,dy,dz,pad
    __shared__ int indS[PB * HN];                      // 2 KB
    __shared__ __align__(16) short wS[PB * 16 * 32];   // 16 KB bf16
    __shared__ __align__(16) short ftS[4 * 64 * 32];   // 16 KB bf16, per-wave
    __shared__ __align__(16) short wtS[PB * KC];       // 30 KB bf16

    const int t = threadIdx.x;
    const int n0 = blockIdx.x * PB;
    const int lane = t & 63;
    const int wid = t >> 6;
    const int l15 = lane & 15;
    const int q = lane >> 4;

    // ---- pre-step: neighbor diffs + indices ----
    for (int it = 0; it < 2; ++it) {
        int pi = t + it * 256;          // 0..511 = (p,h)
        int p = pi >> 5, h = pi & 31;
        int n = n0 + p;
        float dx = 1e9f, dy = 1e9f, dz = 1e9f; int idx = 0;
        if (n < N) {
            idx = inds[n * HN + h];
            dx = s_pts[idx * 3 + 0] - q_pts[n * 3 + 0];
            dy = s_pts[idx * 3 + 1] - q_pts[n * 3 + 1];
            dz = s_pts[idx * 3 + 2] - q_pts[n * 3 + 2];
        }
        indS[pi] = idx;
        nbr[pi * 4 + 0] = dx; nbr[pi * 4 + 1] = dy; nbr[pi * 4 + 2] = dz;
    }
    __syncthreads();

    // ---- phase 1: influence weights -> wS[p][k][h] (thread = (p,k)) ----
    {
        int p = t >> 4, k = t & 15;
        float kx = 0.f, ky = 0.f, kz = 0.f;
        if (k < KK) { kx = kpts[k * 3 + 0]; ky = kpts[k * 3 + 1]; kz = kpts[k * 3 + 2]; }
        for (int h8 = 0; h8 < 4; ++h8) {
            short8 v;
#pragma unroll
            for (int j = 0; j < 8; ++j) {
                int h = h8 * 8 + j;
                float dx = nbr[(p * HN + h) * 4 + 0] - kx;
                float dy = nbr[(p * HN + h) * 4 + 1] - ky;
                float dz = nbr[(p * HN + h) * 4 + 2] - kz;
                float d = sqrtf(dx * dx + dy * dy + dz * dz);
                float w = fmaxf(1.0f - d * INV_EXT, 0.0f);
                if (k >= KK) w = 0.0f;
                v[j] = (short)f32_bf16(w);
            }
            *(short8*)&wS[wIdx(p, k, h8 * 8)] = v;  // conflict-free via swizzle
        }
    }
    // phase-1 writers of wS[p] / consumers in phase 2 are the SAME wave -> no barrier

    // ---- phase 2: per-wave, 4 points: wt[k][c] = w^T @ feat via MFMA ----
    short* ft = &ftS[wid * 2048];
    for (int i = 0; i < 4; ++i) {
        int p = wid * 4 + i;
        {   // 2a: stage featT[c][h] (lane = channel, coalesced gather)
            const int c = lane;
            for (int h8 = 0; h8 < 4; ++h8) {
                short8 v;
#pragma unroll
                for (int j = 0; j < 8; ++j) {
                    int idx = indS[p * HN + h8 * 8 + j];
                    if constexpr (XB) v[j] = (short)xb[idx * CIN + c];
                    else              v[j] = (short)f32_bf16(x[idx * CIN + c]);
                }
                *(short8*)&ft[ftIdx(c, h8 * 8)] = v;
            }
        }
        // 2b: A = w^T[k=l15][h=q*8+j]; B = feat[h][c-tile]; one MFMA per c-tile
        short8 a = *(short8*)&wS[wIdx(p, l15, q * 8)];
#pragma unroll
        for (int ct = 0; ct < 4; ++ct) {
            short8 b = *(short8*)&ft[ftIdx(ct * 16 + l15, q * 8)];
            float4v acc = {0.f, 0.f, 0.f, 0.f};
            acc = __builtin_amdgcn_mfma_f32_16x16x32_bf16(a, b, acc, 0, 0, 0);
            // 2c: C/D layout: row k' = q*4+r, col c = ct*16+l15
#pragma unroll
            for (int r = 0; r < 4; ++r) {
                int kk = q * 4 + r;
                if (kk < KK) {
                    int kc = kk * CIN + ct * 16 + l15;
                    wtS[wtIdx(p, kc)] = (short)f32_bf16(acc[r]);
                }
            }
        }
    }
    __syncthreads();

    // ---- phase 3: OUT[16p x 64d] = wt[16p x 960] @ Wflat[960 x 64], wave owns d-tile ----
    {
        const int d0 = wid * 16;
        float4v acc = {0.f, 0.f, 0.f, 0.f};
        const ushort_t* wtB = WT + (d0 + l15) * KC + q * 8;
#pragma unroll 2
        for (int s = 0; s < 30; ++s) {
            short8 a = *(short8*)&wtS[wtIdx(l15, s * 32 + q * 8)];
            short8 b = *(const short8*)(wtB + s * 32);
            acc = __builtin_amdgcn_mfma_f32_16x16x32_bf16(a, b, acc, 0, 0, 0);
        }
#pragma unroll
        for (int r = 0; r < 4; ++r) {
            int p = q * 4 + r;
            int n = n0 + p;
            if (n < N) out[n * COUT + d0 + l15] = acc[r];
        }
    }
}

// ================= K0: prep (zero stats, transpose W to bf16, optional x->bf16) =================
template <bool XB>
__global__ void prep_kernel(const float* __restrict__ W, const float* __restrict__ x,
                            float* sums, ushort_t* WT, ushort_t* xb, int N)
{
    long gt = (long)blockIdx.x * 256 + threadIdx.x;
    long stride = (long)gridDim.x * 256;
    if (gt < 128) sums[gt] = 0.f;
    for (long i = gt; i < KK * CIN * COUT; i += stride) {
        int k = (int)(i / (CIN * COUT));
        int rem = (int)(i % (CIN * COUT));
        int c = rem >> 6, d = rem & 63;
        WT[d * KC + k * CIN + c] = f32_bf16(W[i]);
    }
    if constexpr (XB) {
        for (long i = gt; i < (long)N * CIN; i += stride) xb[i] = f32_bf16(x[i]);
    }
}

// ================= K2: per-channel sum / sumsq =================
__global__ void stats_kernel(const float* __restrict__ out, float* sums, int N)
{
    __shared__ float r1[256], r2[256];
    int t = threadIdx.x;
    int c = t & 63, rg = t >> 6;
    float s1 = 0.f, s2 = 0.f;
    for (int row = blockIdx.x * 4 + rg; row < N; row += gridDim.x * 4) {
        float v = out[row * 64 + c];
        s1 += v; s2 += v * v;
    }
    r1[t] = s1; r2[t] = s2;
    __syncthreads();
    if (t < 64) {
        s1 = r1[t] + r1[t + 64] + r1[t + 128] + r1[t + 192];
        s2 = r2[t] + r2[t + 64] + r2[t + 128] + r2[t + 192];
        atomicAdd(&sums[t], s1);
        atomicAdd(&sums[64 + t], s2);
    }
}

// ================= K3: instance-norm + LeakyReLU (in place on d_out) =================
__global__ void norm_kernel(float* out, const float* __restrict__ sums, int N)
{
    long total = (long)N * 64 / 4;
    float invN = 1.0f / (float)N;
    for (long i = (long)blockIdx.x * blockDim.x + threadIdx.x; i < total;
         i += (long)gridDim.x * blockDim.x) {
        int cb = (int)((i * 4) & 63);
        float4v v = *(float4v*)&out[i * 4];
        float4v sm = *(const float4v*)&sums[cb];
        float4v sq = *(const float4v*)&sums[64 + cb];
#pragma unroll
        for (int j = 0; j < 4; ++j) {
            float mean = sm[j] * invN;
            float var = fmaxf(sq[j] * invN - mean * mean, 0.f);
            float inv = rsqrtf(var + 1e-5f);
            float val = (v[j] - mean) * inv;
            v[j] = val >= 0.f ? val : 0.1f * val;
        }
        *(float4v*)&out[i * 4] = v;
    }
}

extern "C" void kernel_launch(void* const* d_in, const int* in_sizes, int n_in,
                              void* d_out, int out_size, void* d_ws, size_t ws_size,
                              hipStream_t stream)
{
    const float* q  = (const float*)d_in[0];
    const float* s  = (const float*)d_in[1];
    const int* inds = (const int*)d_in[2];
    const float* x  = (const float*)d_in[3];
    const float* kp = (const float*)d_in[4];
    const float* W  = (const float*)d_in[5];
    float* out = (float*)d_out;
    int N = in_sizes[0] / 3;

    float* sums  = (float*)d_ws;
    ushort_t* WT = (ushort_t*)((char*)d_ws + 1024);
    ushort_t* xb = (ushort_t*)((char*)d_ws + 132096);
    bool useXB = ws_size >= 132096 + (size_t)N * CIN * 2;

    int nblk = (N + PB - 1) / PB;
    if (useXB) {
        prep_kernel<true ><<<512, 256, 0, stream>>>(W, x, sums, WT, xb, N);
        kpconv_main<true ><<<nblk, 256, 0, stream>>>(q, s, inds, x, kp, WT, xb, out, N);
    } else {
        prep_kernel<false><<<512, 256, 0, stream>>>(W, x, sums, WT, xb, N);
        kpconv_main<false><<<nblk, 256, 0, stream>>>(q, s, inds, x, kp, WT, xb, out, N);
    }
    stats_kernel<<<256, 256, 0, stream>>>(out, sums, N);
    norm_kernel<<<1024, 256, 0, stream>>>(out, sums, N);
}

// Round 2
// 280.262 us; speedup vs baseline: 1.1968x; 1.1968x over previous
//
#include <hip/hip_runtime.h>

typedef short short8 __attribute__((ext_vector_type(8)));
typedef short short4v __attribute__((ext_vector_type(4)));
typedef float float4v __attribute__((ext_vector_type(4)));
typedef unsigned short ushort_t;

#define INV_EXT (1.0f / 0.048f)
#define HN 32
#define KK 15
#define CIN 64
#define COUT 64
#define PB 16      /* points per block */
#define KDIM 1024  /* 64 c * 16 k' (k' padded 15->16 with zeros) */

__device__ inline ushort_t f32_bf16(float f) {
    unsigned int u = __float_as_uint(f);
    u += 0x7FFFu + ((u >> 16) & 1u);   // round-to-nearest-even
    return (ushort_t)(u >> 16);
}

// Swizzled element index into wtS row p. kd = c*16 + k'. Granule = 8 elems (16B),
// XOR by (p&7) -> phase-3 reads (p = lane&15 varies) are spread across banks.
__device__ inline int wt2Idx(int p, int kd) {
    return p * KDIM + ((((kd >> 3) ^ (p & 7)) << 3) | (kd & 7));
}

// ================= K1: main KPConv (fused stats) =================
template <bool XB>
__global__ __launch_bounds__(256, 4)
void kpconv_main(const float* __restrict__ q_pts,
                 const float* __restrict__ s_pts,
                 const int*   __restrict__ inds,
                 const float* __restrict__ x,
                 const float* __restrict__ kpts,
                 const ushort_t* __restrict__ WT2,  // [64][1024] bf16, kd=(c,k'16)
                 const ushort_t* __restrict__ xb,   // [N][64] bf16 (if XB)
                 float* __restrict__ out,
                 float* __restrict__ sums, int N)
{
    __shared__ float nX[PB * HN], nY[PB * HN], nZ[PB * HN]; // 6 KB
    __shared__ int indS[PB * HN];                           // 2 KB
    __shared__ __align__(16) short wtS[PB * KDIM];          // 32 KB

    const int t = threadIdx.x;
    const int n0 = blockIdx.x * PB;
    const int lane = t & 63;
    const int wid = t >> 6;
    const int l15 = lane & 15;
    const int q = lane >> 4;

    // ---- pre-step: neighbor diffs + indices (block-wide) ----
    for (int it = 0; it < 2; ++it) {
        int pi = t + it * 256;          // (p,h)
        int p = pi >> 5, h = pi & 31;
        int n = n0 + p;
        float dx = 1e9f, dy = 1e9f, dz = 1e9f; int idx = 0;
        if (n < N) {
            idx = inds[n * HN + h];
            dx = s_pts[idx * 3 + 0] - q_pts[n * 3 + 0];
            dy = s_pts[idx * 3 + 1] - q_pts[n * 3 + 1];
            dz = s_pts[idx * 3 + 2] - q_pts[n * 3 + 2];
        }
        indS[pi] = idx;
        nX[pi] = dx; nY[pi] = dy; nZ[pi] = dz;
    }
    __syncthreads();

    // ---- phase 1: influence weights straight into A-fragment registers ----
    // A-frag (16x16x32): lane holds A[m=l15][k=q*8+j] = w[h=q*8+j][k'=l15]
    int kidx = l15 < KK ? l15 : 0;
    float kx = kpts[kidx * 3 + 0];
    float ky = kpts[kidx * 3 + 1];
    float kz = kpts[kidx * 3 + 2];
    short8 afrag[4];
#pragma unroll
    for (int i = 0; i < 4; ++i) {
        int p = wid * 4 + i;
        int base = p * HN + q * 8;
#pragma unroll
        for (int j = 0; j < 8; ++j) {
            float dx = nX[base + j] - kx;
            float dy = nY[base + j] - ky;
            float dz = nZ[base + j] - kz;
            float d = sqrtf(dx * dx + dy * dy + dz * dz);
            float w = fmaxf(1.0f - d * INV_EXT, 0.0f);
            if (l15 >= KK) w = 0.0f;   // padded kernel point -> zero row
            afrag[i][j] = (short)f32_bf16(w);
        }
    }

    // ---- phase 2: per wave, 4 points: wt[k'][c] = w^T @ feat via MFMA ----
    // B-frag gathered directly from global: lane needs feat[h=q*8+j][c=ct*16+l15]
    for (int i = 0; i < 4; ++i) {
        int p = wid * 4 + i;
        const ushort_t* rpb[8];
        const float* rpf[8];
#pragma unroll
        for (int j = 0; j < 8; ++j) {
            int idx = indS[p * HN + q * 8 + j];
            if constexpr (XB) rpb[j] = xb + (size_t)idx * CIN;
            else              rpf[j] = x + (size_t)idx * CIN;
        }
#pragma unroll
        for (int ct = 0; ct < 4; ++ct) {
            short8 b;
#pragma unroll
            for (int j = 0; j < 8; ++j) {
                if constexpr (XB) b[j] = (short)rpb[j][ct * 16 + l15];
                else              b[j] = (short)f32_bf16(rpf[j][ct * 16 + l15]);
            }
            float4v acc = {0.f, 0.f, 0.f, 0.f};
            acc = __builtin_amdgcn_mfma_f32_16x16x32_bf16(afrag[i], b, acc, 0, 0, 0);
            // C/D: row k' = q*4+r, col c = ct*16+l15. Write k'-quad as b64.
            short4v v;
#pragma unroll
            for (int r = 0; r < 4; ++r) v[r] = (short)f32_bf16(acc[r]);
            int kd = (ct * 16 + l15) * 16 + q * 4;
            *(short4v*)&wtS[wt2Idx(p, kd)] = v;
        }
    }
    __syncthreads();

    // ---- phase 3: OUT[16p x 64d] = wt[16p x 1024] @ WT2 (kd-ordered) ----
    {
        const int d0 = wid * 16;
        float4v acc = {0.f, 0.f, 0.f, 0.f};
        const ushort_t* wb = WT2 + (size_t)(d0 + l15) * KDIM + q * 8;
#pragma unroll 4
        for (int s = 0; s < 32; ++s) {
            short8 a = *(short8*)&wtS[wt2Idx(l15, s * 32 + q * 8)];
            short8 b = *(const short8*)(wb + s * 32);
            acc = __builtin_amdgcn_mfma_f32_16x16x32_bf16(a, b, acc, 0, 0, 0);
        }
        // store + fused per-channel stats
        float s1 = 0.f, s2 = 0.f;
#pragma unroll
        for (int r = 0; r < 4; ++r) {
            int p = q * 4 + r;
            int n = n0 + p;
            float v = acc[r];
            if (n < N) { out[n * COUT + d0 + l15] = v; s1 += v; s2 += v * v; }
        }
        s1 += __shfl_xor(s1, 16); s2 += __shfl_xor(s2, 16);
        s1 += __shfl_xor(s1, 32); s2 += __shfl_xor(s2, 32);
        if (q == 0) {
            atomicAdd(&sums[d0 + l15], s1);
            atomicAdd(&sums[64 + d0 + l15], s2);
        }
    }
}

// ================= K0: prep (zero stats, reorder W to kd layout, x->bf16) ===
template <bool XB>
__global__ void prep_kernel(const float* __restrict__ W, const float* __restrict__ x,
                            float* sums, ushort_t* WT2, ushort_t* xb, int N)
{
    long gt = (long)blockIdx.x * 256 + threadIdx.x;
    long stride = (long)gridDim.x * 256;
    if (gt < 128) sums[gt] = 0.f;
    for (long i = gt; i < COUT * KDIM; i += stride) {
        int d = (int)(i >> 10);
        int rem = (int)(i & 1023);
        int c = rem >> 4, k = rem & 15;
        WT2[i] = (k < KK) ? f32_bf16(W[(k * CIN + c) * COUT + d]) : (ushort_t)0;
    }
    if constexpr (XB) {
        for (long i = gt; i < (long)N * CIN; i += stride) xb[i] = f32_bf16(x[i]);
    }
}

// ================= K2: instance-norm + LeakyReLU (in place on d_out) ========
__global__ void norm_kernel(float* out, const float* __restrict__ sums, int N)
{
    long total = (long)N * 64 / 4;
    float invN = 1.0f / (float)N;
    for (long i = (long)blockIdx.x * blockDim.x + threadIdx.x; i < total;
         i += (long)gridDim.x * blockDim.x) {
        int cb = (int)((i * 4) & 63);
        float4v v = *(float4v*)&out[i * 4];
        float4v sm = *(const float4v*)&sums[cb];
        float4v sq = *(const float4v*)&sums[64 + cb];
#pragma unroll
        for (int j = 0; j < 4; ++j) {
            float mean = sm[j] * invN;
            float var = fmaxf(sq[j] * invN - mean * mean, 0.f);
            float inv = rsqrtf(var + 1e-5f);
            float val = (v[j] - mean) * inv;
            v[j] = val >= 0.f ? val : 0.1f * val;
        }
        *(float4v*)&out[i * 4] = v;
    }
}

extern "C" void kernel_launch(void* const* d_in, const int* in_sizes, int n_in,
                              void* d_out, int out_size, void* d_ws, size_t ws_size,
                              hipStream_t stream)
{
    const float* q  = (const float*)d_in[0];
    const float* s  = (const float*)d_in[1];
    const int* inds = (const int*)d_in[2];
    const float* x  = (const float*)d_in[3];
    const float* kp = (const float*)d_in[4];
    const float* W  = (const float*)d_in[5];
    float* out = (float*)d_out;
    int N = in_sizes[0] / 3;

    float* sums   = (float*)d_ws;
    ushort_t* WT2 = (ushort_t*)((char*)d_ws + 1024);          // 128 KB
    ushort_t* xb  = (ushort_t*)((char*)d_ws + 1024 + 131072);
    bool useXB = ws_size >= 1024 + 131072 + (size_t)N * CIN * 2;

    int nblk = (N + PB - 1) / PB;
    if (useXB) {
        prep_kernel<true ><<<512, 256, 0, stream>>>(W, x, sums, WT2, xb, N);
        kpconv_main<true ><<<nblk, 256, 0, stream>>>(q, s, inds, x, kp, WT2, xb, out, sums, N);
    } else {
        prep_kernel<false><<<512, 256, 0, stream>>>(W, x, sums, WT2, xb, N);
        kpconv_main<false><<<nblk, 256, 0, stream>>>(q, s, inds, x, kp, WT2, xb, out, sums, N);
    }
    norm_kernel<<<1024, 256, 0, stream>>>(out, sums, N);
}

// Round 3
// 196.254 us; speedup vs baseline: 1.7092x; 1.4281x over previous
//
#include <hip/hip_runtime.h>

typedef short short8 __attribute__((ext_vector_type(8)));
typedef short short4v __attribute__((ext_vector_type(4)));
typedef float float4v __attribute__((ext_vector_type(4)));
typedef unsigned short ushort_t;

#define INV_EXT (1.0f / 0.048f)
#define HN 32
#define KK 15
#define CIN 64
#define COUT 64
#define PB 16      /* points per block */
#define KDIM 1024  /* padded 16 k' * 64 c, order defined by jmap below */
#define NSLOT 8    /* stats atomic slots */

__device__ inline ushort_t f32_bf16(float f) {
    unsigned int u = __float_as_uint(f);
    u += 0x7FFFu + ((u >> 16) & 1u);   // round-to-nearest-even
    return (ushort_t)(u >> 16);
}

// wtS element index: row p, logical kd-slot j (0..1023). 16B granule (8 elems)
// XOR-swizzled by p so phase-3 reads (p = lane&15) spread across banks.
__device__ inline int wtJ(int p, int j) {
    return p * KDIM + ((((j >> 3) ^ (p & 7)) << 3) | (j & 7));
}

// ================= K1: main KPConv (fused slotted stats) =================
template <bool XB>
__global__ __launch_bounds__(256, 4)
void kpconv_main(const float* __restrict__ q_pts,
                 const float* __restrict__ s_pts,
                 const int*   __restrict__ inds,
                 const float* __restrict__ x,
                 const float* __restrict__ kpts,
                 const ushort_t* __restrict__ W3,   // [128 kd-octets][64 d][8] bf16
                 const ushort_t* __restrict__ xb,   // [N][64] bf16, channel-permuted
                 float* __restrict__ out,
                 float* __restrict__ sums, int N)
{
    __shared__ float nX[PB * HN], nY[PB * HN], nZ[PB * HN]; // 6 KB
    __shared__ int indS[PB * HN];                           // 2 KB
    __shared__ __align__(16) short wtS[PB * KDIM];          // 32 KB

    const int t = threadIdx.x;
    const int n0 = blockIdx.x * PB;
    const int lane = t & 63;
    const int wid = t >> 6;
    const int l15 = lane & 15;
    const int q = lane >> 4;

    // ---- pre-step: neighbor diffs + indices (block-wide) ----
    for (int it = 0; it < 2; ++it) {
        int pi = t + it * 256;          // (p,h)
        int p = pi >> 5, h = pi & 31;
        int n = n0 + p;
        float dx = 1e9f, dy = 1e9f, dz = 1e9f; int idx = 0;
        if (n < N) {
            idx = inds[n * HN + h];
            dx = s_pts[idx * 3 + 0] - q_pts[n * 3 + 0];
            dy = s_pts[idx * 3 + 1] - q_pts[n * 3 + 1];
            dz = s_pts[idx * 3 + 2] - q_pts[n * 3 + 2];
        }
        indS[pi] = idx;
        nX[pi] = dx; nY[pi] = dy; nZ[pi] = dz;
    }
    __syncthreads();

    // ---- phase 1: influence weights straight into A-fragment registers ----
    // A-frag (16x16x32): lane holds A[m=k'=l15][k=h=q*8+j] = w[h][k']
    int kidx = l15 < KK ? l15 : 0;
    float kx = kpts[kidx * 3 + 0];
    float ky = kpts[kidx * 3 + 1];
    float kz = kpts[kidx * 3 + 2];
    short8 afrag[4];
#pragma unroll
    for (int i = 0; i < 4; ++i) {
        int p = wid * 4 + i;
        int base = p * HN + q * 8;
#pragma unroll
        for (int j = 0; j < 8; ++j) {
            float dx = nX[base + j] - kx;
            float dy = nY[base + j] - ky;
            float dz = nZ[base + j] - kz;
            float d = sqrtf(dx * dx + dy * dy + dz * dz);
            float w = fmaxf(1.0f - d * INV_EXT, 0.0f);
            if (l15 >= KK) w = 0.0f;   // padded kernel point -> zero row
            afrag[i][j] = (short)f32_bf16(w);
        }
    }

    // ---- phase 2: per wave, 4 points: wt[k'][c] = w^T @ feat via MFMA ----
    for (int i = 0; i < 4; ++i) {
        int p = wid * 4 + i;
        short4v L[8];            // XB: one 8B coalesced load covers all 4 ct
        const float* rpf[8];
        if constexpr (XB) {
#pragma unroll
            for (int j = 0; j < 8; ++j) {
                int idx = indS[p * HN + q * 8 + j];
                L[j] = *(const short4v*)(xb + (size_t)idx * CIN + l15 * 4);
            }
        } else {
#pragma unroll
            for (int j = 0; j < 8; ++j)
                rpf[j] = x + (size_t)indS[p * HN + q * 8 + j] * CIN;
        }
#pragma unroll
        for (int ct = 0; ct < 4; ++ct) {
            short8 b;
#pragma unroll
            for (int j = 0; j < 8; ++j) {
                if constexpr (XB) b[j] = L[j][ct];
                else              b[j] = (short)f32_bf16(rpf[j][ct * 16 + l15]);
            }
            float4v acc = {0.f, 0.f, 0.f, 0.f};
            acc = __builtin_amdgcn_mfma_f32_16x16x32_bf16(afrag[i], b, acc, 0, 0, 0);
            // D row m = k' = q*4+r, col n = c = ct*16+l15.
            // kd-slot j(k',c) = quad*4 + r, quad = l15 + 16*(q^ct) + 64*ct
            short4v v;
#pragma unroll
            for (int r = 0; r < 4; ++r) v[r] = (short)f32_bf16(acc[r]);
            int quad = l15 + 16 * (q ^ ct) + 64 * ct;
            *(short4v*)&wtS[wtJ(p, quad * 4)] = v;
        }
    }
    __syncthreads();

    // ---- phase 3: OUT[16p x 64d] = wt[16p x 1024j] @ W3[1024j x 64d] ----
    {
        const int d0 = wid * 16;
        float4v acc = {0.f, 0.f, 0.f, 0.f};
        // B-frag: lane needs W3 j-slots s*32+q*8+(0..7) at col d0+l15 ->
        // octet (s*4+q), contiguous 16B: fully coalesced dwordx4
        const ushort_t* wb = W3 + (size_t)q * 512 + (d0 + l15) * 8;
#pragma unroll 4
        for (int s = 0; s < 32; ++s) {
            short8 a = *(short8*)&wtS[wtJ(l15, s * 32 + q * 8)];
            short8 b = *(const short8*)(wb + (size_t)s * 2048);
            acc = __builtin_amdgcn_mfma_f32_16x16x32_bf16(a, b, acc, 0, 0, 0);
        }
        // store + fused per-channel stats (slotted atomics)
        float s1 = 0.f, s2 = 0.f;
#pragma unroll
        for (int r = 0; r < 4; ++r) {
            int p = q * 4 + r;
            int n = n0 + p;
            float v = acc[r];
            if (n < N) { out[n * COUT + d0 + l15] = v; s1 += v; s2 += v * v; }
        }
        s1 += __shfl_xor(s1, 16); s2 += __shfl_xor(s2, 16);
        s1 += __shfl_xor(s1, 32); s2 += __shfl_xor(s2, 32);
        if (q == 0) {
            int slot = blockIdx.x & (NSLOT - 1);
            atomicAdd(&sums[slot * 128 + d0 + l15], s1);
            atomicAdd(&sums[slot * 128 + 64 + d0 + l15], s2);
        }
    }
}

// ================= K0: prep (zero stats, W->W3 blocked layout, x->xb permuted) ===
template <bool XB>
__global__ void prep_kernel(const float* __restrict__ W, const float* __restrict__ x,
                            float* sums, ushort_t* W3, ushort_t* xb, int N)
{
    long gt = (long)blockIdx.x * 256 + threadIdx.x;
    long stride = (long)gridDim.x * 256;
    if (gt < NSLOT * 128) sums[gt] = 0.f;
    for (long i = gt; i < COUT * KDIM; i += stride) {
        int d = (int)((i >> 3) & 63);
        int j = (int)(((i >> 9) << 3) | (i & 7));  // kd-slot
        int quad = j >> 2, r = j & 3;
        int l15 = quad & 15, e = (quad >> 4) & 3, ct = quad >> 6;
        int q2 = e ^ ct;
        int k = q2 * 4 + r, c = ct * 16 + l15;
        W3[i] = (k < KK) ? f32_bf16(W[(k * CIN + c) * COUT + d]) : (ushort_t)0;
    }
    if constexpr (XB) {
        // channel-permuted bf16 copy: xb[n][c'] = x[n][(c'&3)*16 + (c'>>2)]
        for (long i = gt; i < (long)N * CIN; i += stride) {
            int cp = (int)(i & 63);
            int c = (cp & 3) * 16 + (cp >> 2);
            xb[i] = f32_bf16(x[(i & ~63L) + c]);
        }
    }
}

// ================= K2: reduce slots + instance-norm + LeakyReLU ========
__global__ void norm_kernel(float* out, const float* __restrict__ sums, int N)
{
    __shared__ float meanS[64], invS[64];
    int t = threadIdx.x;
    if (t < 64) {
        float s1 = 0.f, s2 = 0.f;
#pragma unroll
        for (int sl = 0; sl < NSLOT; ++sl) {
            s1 += sums[sl * 128 + t];
            s2 += sums[sl * 128 + 64 + t];
        }
        float invN = 1.0f / (float)N;
        float mean = s1 * invN;
        float var = fmaxf(s2 * invN - mean * mean, 0.f);
        meanS[t] = mean;
        invS[t] = rsqrtf(var + 1e-5f);
    }
    __syncthreads();
    long total = (long)N * 64 / 4;
    for (long i = (long)blockIdx.x * blockDim.x + t; i < total;
         i += (long)gridDim.x * blockDim.x) {
        int cb = (int)((i * 4) & 63);
        float4v v = *(float4v*)&out[i * 4];
#pragma unroll
        for (int j = 0; j < 4; ++j) {
            float val = (v[j] - meanS[cb + j]) * invS[cb + j];
            v[j] = val >= 0.f ? val : 0.1f * val;
        }
        *(float4v*)&out[i * 4] = v;
    }
}

extern "C" void kernel_launch(void* const* d_in, const int* in_sizes, int n_in,
                              void* d_out, int out_size, void* d_ws, size_t ws_size,
                              hipStream_t stream)
{
    const float* q  = (const float*)d_in[0];
    const float* s  = (const float*)d_in[1];
    const int* inds = (const int*)d_in[2];
    const float* x  = (const float*)d_in[3];
    const float* kp = (const float*)d_in[4];
    const float* W  = (const float*)d_in[5];
    float* out = (float*)d_out;
    int N = in_sizes[0] / 3;

    float* sums  = (float*)d_ws;                                // 4 KB
    ushort_t* W3 = (ushort_t*)((char*)d_ws + 4096);             // 128 KB
    ushort_t* xb = (ushort_t*)((char*)d_ws + 4096 + 131072);
    bool useXB = ws_size >= 4096 + 131072 + (size_t)N * CIN * 2;

    int nblk = (N + PB - 1) / PB;
    if (useXB) {
        prep_kernel<true ><<<512, 256, 0, stream>>>(W, x, sums, W3, xb, N);
        kpconv_main<true ><<<nblk, 256, 0, stream>>>(q, s, inds, x, kp, W3, xb, out, sums, N);
    } else {
        prep_kernel<false><<<512, 256, 0, stream>>>(W, x, sums, W3, xb, N);
        kpconv_main<false><<<nblk, 256, 0, stream>>>(q, s, inds, x, kp, W3, xb, out, sums, N);
    }
    norm_kernel<<<1024, 256, 0, stream>>>(out, sums, N);
}

// Round 5
// 189.057 us; speedup vs baseline: 1.7742x; 1.0381x over previous
//
#include <hip/hip_runtime.h>

typedef short short8 __attribute__((ext_vector_type(8)));
typedef short short4v __attribute__((ext_vector_type(4)));
typedef float float4v __attribute__((ext_vector_type(4)));
typedef unsigned short ushort_t;

#define INV_EXT (1.0f / 0.048f)
#define HN 32
#define KK 15
#define CIN 64
#define COUT 64
#define PB 16      /* points per block */
#define KDIM 1024  /* padded 16 k' * 64 c, order defined by j-map */
#define NSLOT 16   /* stats atomic slots */

__device__ inline ushort_t f32_bf16(float f) {
    unsigned int u = __float_as_uint(f);
    u += 0x7FFFu + ((u >> 16) & 1u);   // round-to-nearest-even
    return (ushort_t)(u >> 16);
}

// wtS element index: row p, logical kd-slot j (0..1023). 16B granule (8 elems)
// XOR-swizzled by p so phase-3 reads (p = lane&15) spread across banks.
__device__ inline int wtJ(int p, int j) {
    return p * KDIM + ((((j >> 3) ^ (p & 7)) << 3) | (j & 7));
}

// ================= K1: main KPConv (fused slotted stats) =================
template <bool XB>
__global__ __launch_bounds__(256, 4)
void kpconv_main(const float* __restrict__ q_pts,
                 const float* __restrict__ s_pts,
                 const int*   __restrict__ inds,
                 const float* __restrict__ x,
                 const float* __restrict__ kpts,
                 const ushort_t* __restrict__ W3,   // [128 kd-octets][64 d][8] bf16
                 const ushort_t* __restrict__ xb,   // [N][64] bf16, channel-permuted
                 float* __restrict__ out,
                 float* __restrict__ sums, int N)
{
    __shared__ float nX[PB * HN], nY[PB * HN], nZ[PB * HN]; // 6 KB
    __shared__ int indS[PB * HN];                           // 2 KB
    __shared__ __align__(16) short wtS[PB * KDIM];          // 32 KB

    const int t = threadIdx.x;
    const int n0 = blockIdx.x * PB;
    const int lane = t & 63;
    const int wid = t >> 6;
    const int l15 = lane & 15;
    const int q = lane >> 4;

    // ---- pre-step: neighbor diffs + indices (block-wide) ----
    for (int it = 0; it < 2; ++it) {
        int pi = t + it * 256;          // (p,h)
        int p = pi >> 5, h = pi & 31;
        int n = n0 + p;
        float dx = 1e9f, dy = 1e9f, dz = 1e9f; int idx = 0;
        if (n < N) {
            idx = inds[n * HN + h];
            dx = s_pts[idx * 3 + 0] - q_pts[n * 3 + 0];
            dy = s_pts[idx * 3 + 1] - q_pts[n * 3 + 1];
            dz = s_pts[idx * 3 + 2] - q_pts[n * 3 + 2];
        }
        indS[pi] = idx;
        nX[pi] = dx; nY[pi] = dy; nZ[pi] = dz;
    }
    __syncthreads();

    // ---- phase 1: influence weights straight into A-fragment registers ----
    // A-frag (16x16x32): lane holds A[m=k'=l15][k=h=q*8+j] = w[h][k']
    int kidx = l15 < KK ? l15 : 0;
    float kx = kpts[kidx * 3 + 0];
    float ky = kpts[kidx * 3 + 1];
    float kz = kpts[kidx * 3 + 2];
    // pad kernel point (l15 >= KK): push it 3e4 away -> w clamps to 0,
    // removing 32 per-element cndmasks.
    if (l15 >= KK) { kx = 3e4f; ky = 3e4f; kz = 3e4f; }
    short8 afrag[4];
#pragma unroll
    for (int i = 0; i < 4; ++i) {
        int p = wid * 4 + i;
        int base = p * HN + q * 8;
#pragma unroll
        for (int j = 0; j < 8; ++j) {
            float dx = nX[base + j] - kx;
            float dy = nY[base + j] - ky;
            float dz = nZ[base + j] - kz;
            float d = __builtin_amdgcn_sqrtf(fmaf(dx, dx, fmaf(dy, dy, dz * dz)));
            float w = fmaxf(fmaf(d, -INV_EXT, 1.0f), 0.0f);
            afrag[i][j] = (short)f32_bf16(w);
        }
    }

    // ---- phase 2: per wave, 4 points: wt[k'][c] = w^T @ feat via MFMA ----
    for (int i = 0; i < 4; ++i) {
        int p = wid * 4 + i;
        short4v L[8];            // XB: one 8B coalesced load covers all 4 ct
        const float* rpf[8];
        if constexpr (XB) {
#pragma unroll
            for (int j = 0; j < 8; ++j) {
                int idx = indS[p * HN + q * 8 + j];
                L[j] = *(const short4v*)(xb + (size_t)idx * CIN + l15 * 4);
            }
        } else {
#pragma unroll
            for (int j = 0; j < 8; ++j)
                rpf[j] = x + (size_t)indS[p * HN + q * 8 + j] * CIN;
        }
#pragma unroll
        for (int ct = 0; ct < 4; ++ct) {
            short8 b;
#pragma unroll
            for (int j = 0; j < 8; ++j) {
                if constexpr (XB) b[j] = L[j][ct];
                else              b[j] = (short)f32_bf16(rpf[j][ct * 16 + l15]);
            }
            float4v acc = {0.f, 0.f, 0.f, 0.f};
            acc = __builtin_amdgcn_mfma_f32_16x16x32_bf16(afrag[i], b, acc, 0, 0, 0);
            // D row m = k' = q*4+r, col n = c = ct*16+l15.
            // kd-slot j(k',c) = quad*4 + r, quad = l15 + 16*(q^ct) + 64*ct
            short4v v;
#pragma unroll
            for (int r = 0; r < 4; ++r) v[r] = (short)f32_bf16(acc[r]);
            int quad = l15 + 16 * (q ^ ct) + 64 * ct;
            *(short4v*)&wtS[wtJ(p, quad * 4)] = v;
        }
    }
    __syncthreads();

    // ---- phase 3: OUT[16p x 64d] = wt[16p x 1024j] @ W3[1024j x 64d] ----
    {
        const int d0 = wid * 16;
        float4v acc = {0.f, 0.f, 0.f, 0.f};
        // B-frag: lane needs W3 j-slots s*32+q*8+(0..7) at col d0+l15 ->
        // octet (s*4+q), contiguous 16B: fully coalesced dwordx4
        const ushort_t* wb = W3 + (size_t)q * 512 + (d0 + l15) * 8;
#pragma unroll 4
        for (int s = 0; s < 32; ++s) {
            short8 a = *(short8*)&wtS[wtJ(l15, s * 32 + q * 8)];
            short8 b = *(const short8*)(wb + (size_t)s * 2048);
            acc = __builtin_amdgcn_mfma_f32_16x16x32_bf16(a, b, acc, 0, 0, 0);
        }
        // store + fused per-channel stats (slotted atomics)
        float s1 = 0.f, s2 = 0.f;
#pragma unroll
        for (int r = 0; r < 4; ++r) {
            int p = q * 4 + r;
            int n = n0 + p;
            float v = acc[r];
            if (n < N) { out[n * COUT + d0 + l15] = v; s1 += v; s2 += v * v; }
        }
        s1 += __shfl_xor(s1, 16); s2 += __shfl_xor(s2, 16);
        s1 += __shfl_xor(s1, 32); s2 += __shfl_xor(s2, 32);
        if (q == 0) {
            int slot = blockIdx.x & (NSLOT - 1);
            atomicAdd(&sums[slot * 128 + d0 + l15], s1);
            atomicAdd(&sums[slot * 128 + 64 + d0 + l15], s2);
        }
    }
}

// ================= K0: prep (zero stats, W->W3 blocked layout, x->xb permuted) ===
template <bool XB>
__global__ void prep_kernel(const float* __restrict__ W, const float* __restrict__ x,
                            float* sums, ushort_t* W3, ushort_t* xb, int N)
{
    long gt = (long)blockIdx.x * 256 + threadIdx.x;
    long stride = (long)gridDim.x * 256;
    if (gt < NSLOT * 128) sums[gt] = 0.f;
    for (long i = gt; i < COUT * KDIM; i += stride) {
        int d = (int)((i >> 3) & 63);
        int j = (int)(((i >> 9) << 3) | (i & 7));  // kd-slot
        int quad = j >> 2, r = j & 3;
        int l15 = quad & 15, e = (quad >> 4) & 3, ct = quad >> 6;
        int k = (e ^ ct) * 4 + r, c = ct * 16 + l15;
        W3[i] = (k < KK) ? f32_bf16(W[(k * CIN + c) * COUT + d]) : (ushort_t)0;
    }
    if constexpr (XB) {
        // xb[n][tt*4+ct] = bf16(x[n][ct*16+tt]); read AND write coalesced
        long nq = (long)N * 16;
        for (long iq = gt; iq < nq; iq += stride) {
            long n = iq >> 4; int tt = (int)(iq & 15);
            const float* xp = x + n * 64;
            short4v v;
            v[0] = (short)f32_bf16(xp[tt]);
            v[1] = (short)f32_bf16(xp[tt + 16]);
            v[2] = (short)f32_bf16(xp[tt + 32]);
            v[3] = (short)f32_bf16(xp[tt + 48]);
            *(short4v*)(xb + n * 64 + tt * 4) = v;
        }
    }
}

// ================= K2: reduce slots + instance-norm + LeakyReLU ========
__global__ void norm_kernel(float* out, const float* __restrict__ sums, int N)
{
    __shared__ float meanS[64], invS[64];
    int t = threadIdx.x;
    if (t < 64) {
        float s1 = 0.f, s2 = 0.f;
#pragma unroll
        for (int sl = 0; sl < NSLOT; ++sl) {
            s1 += sums[sl * 128 + t];
            s2 += sums[sl * 128 + 64 + t];
        }
        float invN = 1.0f / (float)N;
        float mean = s1 * invN;
        float var = fmaxf(s2 * invN - mean * mean, 0.f);
        meanS[t] = mean;
        invS[t] = rsqrtf(var + 1e-5f);
    }
    __syncthreads();
    long total = (long)N * 64 / 4;
    for (long i = (long)blockIdx.x * blockDim.x + t; i < total;
         i += (long)gridDim.x * blockDim.x) {
        int cb = (int)((i * 4) & 63);
        float4v v = *(float4v*)&out[i * 4];
#pragma unroll
        for (int j = 0; j < 4; ++j) {
            float val = (v[j] - meanS[cb + j]) * invS[cb + j];
            v[j] = val >= 0.f ? val : 0.1f * val;
        }
        *(float4v*)&out[i * 4] = v;
    }
}

extern "C" void kernel_launch(void* const* d_in, const int* in_sizes, int n_in,
                              void* d_out, int out_size, void* d_ws, size_t ws_size,
                              hipStream_t stream)
{
    const float* q  = (const float*)d_in[0];
    const float* s  = (const float*)d_in[1];
    const int* inds = (const int*)d_in[2];
    const float* x  = (const float*)d_in[3];
    const float* kp = (const float*)d_in[4];
    const float* W  = (const float*)d_in[5];
    float* out = (float*)d_out;
    int N = in_sizes[0] / 3;

    float* sums  = (float*)d_ws;                                // 8 KB
    ushort_t* W3 = (ushort_t*)((char*)d_ws + 8192);             // 128 KB
    ushort_t* xb = (ushort_t*)((char*)d_ws + 8192 + 131072);
    bool useXB = ws_size >= 8192 + 131072 + (size_t)N * CIN * 2;

    int nblk = (N + PB - 1) / PB;
    if (useXB) {
        prep_kernel<true ><<<512, 256, 0, stream>>>(W, x, sums, W3, xb, N);
        kpconv_main<true ><<<nblk, 256, 0, stream>>>(q, s, inds, x, kp, W3, xb, out, sums, N);
    } else {
        prep_kernel<false><<<512, 256, 0, stream>>>(W, x, sums, W3, xb, N);
        kpconv_main<false><<<nblk, 256, 0, stream>>>(q, s, inds, x, kp, W3, xb, out, sums, N);
    }
    norm_kernel<<<1024, 256, 0, stream>>>(out, sums, N);
}